// Round 9
// baseline (218.691 us; speedup 1.0000x reference)
//
#include <hip/hip_runtime.h>
#include <hip/hip_bf16.h>
#include <hip/hip_cooperative_groups.h>

// MaskedDenseLayer round 9: round-7's two proven phases fused into ONE
// cooperative kernel with grid.sync() between them -- removes the second
// launch (~10us, rocprof.md) and the dependent-node drain that rounds 5-7
// paid. Phase logic is byte-identical to round 7 (mask->bit transpose and
// kern->bf16 step-major via 64KB-contiguous streams + register transpose;
// barrier-free 13-MFMA main loop), except A-frags now gather from f32 x
// directly (round 8 showed that costs ~nothing), so the xt pass is gone.
//
// Coop geometry: grid 512 x 512thr = 2 blocks/CU co-resident (27KB LDS,
// <=128 VGPR via __launch_bounds__(512,4)). Phase-1 work = 929 sub-block
// units, 2 per block (tid>>8). Fallback: if hipLaunchCooperativeKernel is
// rejected, launch the same phases as two classic kernels.

namespace cg = cooperative_groups;

#define IN_DIM 784
#define OUT_DIM 1024
#define BS 512

typedef __attribute__((ext_vector_type(8))) short bf16x8;
typedef __attribute__((ext_vector_type(16))) float f32x16;

#define KQ_OFF 0u            // 16B slots [32 ot][4 q][13 t][64 lane]
#define MB_OFF (2u << 20)    // u8 [16 s][32 ot][4 q][13 t][64 lane]

static __device__ inline short f2bf(float f) {
    __hip_bfloat16 h = __float2bfloat16(f);   // RNE
    short r; __builtin_memcpy(&r, &h, 2); return r;
}

static __device__ inline void c_to_qt(int c, int& q, int& t) {
    if (c < 13) { q = 0; t = c; }
    else        { q = 1 + (c - 13) / 12; t = (c - 13) % 12; }
}

static __device__ inline bf16x8 pack8(float4 a, float4 b) {
    bf16x8 r;
    r[0]=f2bf(a.x); r[1]=f2bf(a.y); r[2]=f2bf(a.z); r[3]=f2bf(a.w);
    r[4]=f2bf(b.x); r[5]=f2bf(b.y); r[6]=f2bf(b.z); r[7]=f2bf(b.w);
    return r;
}

// ---- phase 1: one 256-thread unit sb in [0,929) ----
static __device__ inline void phase1_dev(int sb, int t2,
    const float* __restrict__ masks, const float* __restrict__ kern,
    unsigned char* __restrict__ ws)
{
    if (sb < 784) {
        // masks -> transposed bit-bytes; 64KB contiguous read
        const int s = sb / 49, c = sb % 49;
        const float4* mrow =
            (const float4*)(masks + ((size_t)s * IN_DIM + c * 16) * OUT_DIM) + t2;
        unsigned nib[16];
#pragma unroll
        for (int r = 0; r < 16; ++r) {
            float4 v = mrow[r * 256];
            nib[r] = (v.x != 0.f ? 1u : 0u) | (v.y != 0.f ? 2u : 0u)
                   | (v.z != 0.f ? 4u : 0u) | (v.w != 0.f ? 8u : 0u);
        }
        int q, t; c_to_qt(c, q, t);
        const int ot = t2 >> 3;
        const size_t base32 = ((((size_t)(s * 32 + ot) * 4 + q) * 13 + t) * 16);
        unsigned* mb = (unsigned*)(ws + MB_OFF);
#pragma unroll
        for (int khl = 0; khl < 2; ++khl) {
            unsigned wd = 0;
#pragma unroll
            for (int j = 0; j < 4; ++j) {
                unsigned by = 0;
#pragma unroll
                for (int e = 0; e < 8; ++e)
                    by |= ((nib[khl * 8 + e] >> j) & 1u) << e;
                wd |= by << (8 * j);
            }
            mb[base32 + khl * 8 + (t2 & 7)] = wd;
        }
    } else if (sb < 833) {
        // kern -> bf16 step-major; 64KB contiguous read
        const int c = sb - 784;
        const float4* krow = (const float4*)(kern + (size_t)c * 16 * OUT_DIM) + t2;
        unsigned short ku[16][4];
#pragma unroll
        for (int r = 0; r < 16; ++r) {
            float4 v = krow[r * 256];
            ku[r][0] = (unsigned short)f2bf(v.x);
            ku[r][1] = (unsigned short)f2bf(v.y);
            ku[r][2] = (unsigned short)f2bf(v.z);
            ku[r][3] = (unsigned short)f2bf(v.w);
        }
        int q, t; c_to_qt(c, q, t);
        const int ot = t2 >> 3;
        uint4* kq = (uint4*)(ws + KQ_OFF) + ((size_t)(ot * 4 + q) * 13 + t) * 64;
#pragma unroll
        for (int khl = 0; khl < 2; ++khl)
#pragma unroll
            for (int j = 0; j < 4; ++j) {
                uint4 slot;
                slot.x = (unsigned)ku[khl*8+0][j] | ((unsigned)ku[khl*8+1][j] << 16);
                slot.y = (unsigned)ku[khl*8+2][j] | ((unsigned)ku[khl*8+3][j] << 16);
                slot.z = (unsigned)ku[khl*8+4][j] | ((unsigned)ku[khl*8+5][j] << 16);
                slot.w = (unsigned)ku[khl*8+6][j] | ((unsigned)ku[khl*8+7][j] << 16);
                kq[khl * 32 + (t2 & 7) * 4 + j] = slot;
            }
    } else if (sb < 929) {
        // zero pad bit-bytes: (s,ot), q in {1,2,3}, t==12  -> B == 0 exactly
        const int g   = (sb - 833) * 256 + t2;
        const int run = g >> 4, off = g & 15;
        const int sot = run / 3, q = run % 3 + 1;
        ((unsigned*)(ws + MB_OFF))[((size_t)(sot * 4 + q) * 13 + 12) * 16 + off] = 0u;
    }
}

// ---- phase 2: grouped GEMM block bid = s*? (s = bid&15, ot = bid>>4) ----
static __device__ inline void phase2_dev(int bid, int tid,
    const float* __restrict__ x, const int* __restrict__ state,
    const unsigned char* __restrict__ ws, const float* __restrict__ bias,
    float* __restrict__ out)
{
    __shared__ int   list[BS];
    __shared__ int   cnt;
    __shared__ float red[3][2][16][64];   // [q-1][m][reg][lane] 24 KB

    const int lane = tid & 63;
    const int w    = tid >> 6;
    const int q    = w & 3;
    const int m    = w >> 2;
    const int s    = bid & 15;
    const int ot   = bid >> 4;

    if (tid == 0) cnt = 0;
    __syncthreads();
    { int st = state[tid]; if (st == s) { int p = atomicAdd(&cnt, 1); list[p] = tid; } }
    __syncthreads();
    const int ns = cnt;
    if (ns == 0) return;

    const int l31 = lane & 31, khl = lane >> 5;
    const int qoff = q ? (16 + 192 * q) : 0;

    // A preload: 13 bf16x8 frags gathered from this lane's f32 x row
    int ridx = m * 32 + l31; if (ridx >= ns) ridx = ns - 1;
    const float* xr = x + (size_t)list[ridx] * IN_DIM;
    bf16x8 a[13];
#pragma unroll
    for (int t = 0; t < 13; ++t) {
        const int off = ((q && t == 12) ? qoff : qoff + t * 16) + khl * 8;
        a[t] = pack8(*(const float4*)(xr + off), *(const float4*)(xr + off + 4));
    }

    // K-loop: coalesced kern frag + bit-expand, no barriers
    const uint4* kp = (const uint4*)(ws + KQ_OFF) + ((size_t)(ot * 4 + q) * 13) * 64 + lane;
    const unsigned char* bp = ws + MB_OFF + (((size_t)(s * 32 + ot) * 4 + q) * 13) * 64 + lane;

    f32x16 acc;
#pragma unroll
    for (int r = 0; r < 16; ++r) acc[r] = 0.f;

#pragma unroll
    for (int t = 0; t < 13; ++t) {
        uint4 kv = kp[t * 64];
        unsigned bb = bp[t * 64];
        uint4 bv;
        bv.x = kv.x & ((bb &   1u ? 0xFFFFu : 0u) | (bb &   2u ? 0xFFFF0000u : 0u));
        bv.y = kv.y & ((bb &   4u ? 0xFFFFu : 0u) | (bb &   8u ? 0xFFFF0000u : 0u));
        bv.z = kv.z & ((bb &  16u ? 0xFFFFu : 0u) | (bb &  32u ? 0xFFFF0000u : 0u));
        bv.w = kv.w & ((bb &  64u ? 0xFFFFu : 0u) | (bb & 128u ? 0xFFFF0000u : 0u));
        bf16x8 bfr; __builtin_memcpy(&bfr, &bv, 16);
        acc = __builtin_amdgcn_mfma_f32_32x32x16_bf16(a[t], bfr, acc, 0, 0, 0);
    }

    // reduce 4 K-quarters, fused bias+relu store
    if (q) {
#pragma unroll
        for (int j = 0; j < 16; ++j) red[q - 1][m][j][lane] = acc[j];
    }
    __syncthreads();
    if (q == 0) {
        const float bv = bias[ot * 32 + l31];
#pragma unroll
        for (int j = 0; j < 16; ++j) {
            float v = acc[j] + red[0][m][j][lane] + red[1][m][j][lane] + red[2][m][j][lane];
            const int row = (j & 3) + 8 * (j >> 2) + 4 * khl;   // C/D layout
            const int sr  = m * 32 + row;
            if (sr < ns) {
                float o = v + bv;
                out[(size_t)list[sr] * OUT_DIM + ot * 32 + l31] = o > 0.f ? o : 0.f;
            }
        }
    }
}

__global__ __launch_bounds__(512, 4) void made_coop(
    const float* __restrict__ x, const int* __restrict__ state,
    const float* __restrict__ masks, const float* __restrict__ kern,
    const float* __restrict__ bias, float* __restrict__ out,
    unsigned char* __restrict__ ws)
{
    const int tid = threadIdx.x, bid = blockIdx.x;
    phase1_dev(bid * 2 + (tid >> 8), tid & 255, masks, kern, ws);
    __threadfence();                 // make ws writes device-visible
    cg::this_grid().sync();
    phase2_dev(bid, tid, x, state, ws, bias, out);
}

// ---- fallback: same phases as two classic kernels ----
__global__ __launch_bounds__(256) void made_p1(
    const float* __restrict__ masks, const float* __restrict__ kern,
    unsigned char* __restrict__ ws)
{
    phase1_dev(blockIdx.x, threadIdx.x, masks, kern, ws);
}

__global__ __launch_bounds__(512, 4) void made_p2(
    const float* __restrict__ x, const int* __restrict__ state,
    const unsigned char* __restrict__ ws, const float* __restrict__ bias,
    float* __restrict__ out)
{
    phase2_dev(blockIdx.x, threadIdx.x, x, state, ws, bias, out);
}

extern "C" void kernel_launch(void* const* d_in, const int* in_sizes, int n_in,
                              void* d_out, int out_size, void* d_ws, size_t ws_size,
                              hipStream_t stream) {
    (void)in_sizes; (void)n_in; (void)out_size; (void)ws_size;
    const float* x     = (const float*)d_in[0];
    const int*   state = (const int*)  d_in[1];
    const float* masks = (const float*)d_in[2];
    const float* kern  = (const float*)d_in[3];
    const float* b0    = (const float*)d_in[4];
    float* out = (float*)d_out;
    unsigned char* ws = (unsigned char*)d_ws;

    void* args[7] = { (void*)&x, (void*)&state, (void*)&masks, (void*)&kern,
                      (void*)&b0, (void*)&out, (void*)&ws };
    hipError_t rc = hipLaunchCooperativeKernel((const void*)made_coop,
                                               dim3(512), dim3(512), args, 0, stream);
    if (rc != hipSuccess) {
        made_p1<<<dim3(929), dim3(256), 0, stream>>>(masks, kern, ws);
        made_p2<<<dim3(512), dim3(512), 0, stream>>>(x, state, ws, b0, out);
    }
}

// Round 10
// 44.040 us; speedup vs baseline: 4.9658x; 4.9658x over previous
//
#include <hip/hip_runtime.h>
#include <hip/hip_bf16.h>

// MaskedDenseLayer round 10: round-8 single fused kernel + T3/T4 counted
// vmcnt. Round 8 lost to the per-stage vmcnt(0) drain (911 GB/s, 14% duty);
// here stage t+1's loads stay in FLIGHT across the barrier (asm vmcnt(2)),
// 3-buffer ring, drain only at the last stage.
//
// Grid 512 = (s)*32+(ot 32 cols); same-ot blocks share an XCD L2 (bid%8).
// Block 512 thr = 8 waves = (q: 16-row slice) x (m: 32-sample frag).
// K = 13 stages of 64 rows (stage 12 = rows 768..783 duplicated to keep the
// load pattern uniform; only q==0 consumes it). Per stage per wave: exactly
// 2 global_load_lds dwordx4 (kern+mask, 1KB each, wave-uniform LDS base).
// Iter: [issue S(t+1) -> s_waitcnt vmcnt(2) -> s_barrier -> consume S(t)].
// Ring safety: writer of buf (t+1)%3 passed barrier#(t-1) > all consumes of
// S(t-2), the buffer's previous occupant. All non-staging global reads are
// forced complete before the loop so the vmcnt counts stay pure.
// Consume: 32 ds_read_b32 (banks=cols, 2-way only) + mul + f2bf + 1 MFMA
// (mfma_f32_32x32x16_bf16). K-slices reduced via LDS alias; bias+relu store.

#define IN_DIM 784
#define OUT_DIM 1024
#define BS 512

typedef __attribute__((ext_vector_type(8))) short bf16x8;
typedef __attribute__((ext_vector_type(16))) float f32x16;

static __device__ inline short f2bf(float f) {
    __hip_bfloat16 h = __float2bfloat16(f);   // RNE
    short r; __builtin_memcpy(&r, &h, 2); return r;
}

static __device__ inline void gload_lds16(const float* g, float* lds_base_uniform) {
    __builtin_amdgcn_global_load_lds(
        (const __attribute__((address_space(1))) void*)g,
        (__attribute__((address_space(3))) void*)lds_base_uniform, 16, 0, 0);
}

static __device__ inline bf16x8 pack8(float4 a, float4 b) {
    bf16x8 r;
    r[0]=f2bf(a.x); r[1]=f2bf(a.y); r[2]=f2bf(a.z); r[3]=f2bf(a.w);
    r[4]=f2bf(b.x); r[5]=f2bf(b.y); r[6]=f2bf(b.z); r[7]=f2bf(b.w);
    return r;
}

__global__ __launch_bounds__(512, 4) void made_fused2(
    const float* __restrict__ x,      // [512, 784]
    const int*   __restrict__ state,  // [512]
    const float* __restrict__ masks,  // [16, 784, 1024]
    const float* __restrict__ kern,   // [784, 1024]
    const float* __restrict__ bias,   // [1024]
    float*       __restrict__ out)    // [512, 1024]
{
    __shared__ float tiles[3][2][64][32];   // [buf][kern/mask][row][col] 48 KB
    __shared__ int   list[BS];
    __shared__ int   cnt;

    const int tid  = threadIdx.x;
    const int lane = tid & 63;
    const int w    = tid >> 6;
    const int q    = w & 3;               // 16-row k-slice within a stage
    const int m    = w >> 2;              // sample frag (rows mb+m*32 ..+31)
    const int bid  = blockIdx.x;
    const int s    = bid >> 5;
    const int ot   = bid & 31;
    const int oc0  = ot * 32;
    const int l31  = lane & 31, khl = lane >> 5;

    const float* mS = masks + (size_t)s * IN_DIM * OUT_DIM;

    // ---- build the state's sample list ----
    if (tid == 0) cnt = 0;
    __syncthreads();
    { int st = state[tid]; if (st == s) { int p = atomicAdd(&cnt, 1); list[p] = tid; } }
    __syncthreads();
    const int ns = cnt;

    // bias: load now, keep alive (no global loads inside the counted loop)
    const float biasv = bias[oc0 + l31];
    asm volatile("" :: "v"(biasv));

    // stage t into buffer b: exactly 2 vmcnt ops per wave, uniform all waves
    auto stage = [&](int t, int b) {
        const int r  = w * 8 + (lane >> 3);           // tile row this lane fills
        const int gr = (t == 12) ? 768 + (r & 15) : t * 64 + r;
        const size_t go = (size_t)gr * OUT_DIM + oc0 + (lane & 7) * 4;
        gload_lds16(kern + go, &tiles[b][0][w * 8][0]);
        gload_lds16(mS   + go, &tiles[b][1][w * 8][0]);
    };

    float (*red)[3][16][64] = (float (*)[3][16][64])tiles;   // 24 KB alias

    for (int mb = 0; mb < ns; mb += 64) {
        const bool active = (mb + m * 32) < ns;

        // ---- A preload: 13 bf16x8 from this lane's gathered x row; the
        //      f2bf conversions force completion before the counted loop ----
        int r0 = mb + m * 32 + l31; if (r0 >= ns) r0 = ns - 1;
        const float* xr = x + (size_t)list[r0] * IN_DIM;
        bf16x8 a[13];
#pragma unroll
        for (int t = 0; t < 12; ++t) {
            const int off = t * 64 + q * 16 + khl * 8;
            a[t] = pack8(*(const float4*)(xr + off), *(const float4*)(xr + off + 4));
        }
        a[12] = pack8(*(const float4*)(xr + 768 + khl * 8),
                      *(const float4*)(xr + 772 + khl * 8));

        f32x16 acc;
#pragma unroll
        for (int r = 0; r < 16; ++r) acc[r] = 0.f;

        // ---- prologue: 2 stages in flight ----
        stage(0, 0);
        stage(1, 1);
        __builtin_amdgcn_sched_barrier(0);

#pragma unroll
        for (int t = 0; t < 13; ++t) {
            if (t + 1 < 13) stage(t + 1, (t + 1) % 3);
            if (t < 12) asm volatile("s_waitcnt vmcnt(2)" ::: "memory");
            else        asm volatile("s_waitcnt vmcnt(0)" ::: "memory");
            __builtin_amdgcn_sched_barrier(0);
            __builtin_amdgcn_s_barrier();
            __builtin_amdgcn_sched_barrier(0);

            const int buf = t % 3;
            if (active && (t < 12 || q == 0)) {
                bf16x8 bfr;
#pragma unroll
                for (int e = 0; e < 8; ++e) {
                    const int row = ((t < 12) ? q * 16 : 0) + khl * 8 + e;
                    bfr[e] = f2bf(tiles[buf][0][row][l31] * tiles[buf][1][row][l31]);
                }
                acc = __builtin_amdgcn_mfma_f32_32x32x16_bf16(a[t], bfr, acc, 0, 0, 0);
            }
        }

        // ---- reduce 4 k-slices (LDS alias over tiles), bias+relu store ----
        __syncthreads();                  // full fence before aliasing tiles
        if (q && active) {
#pragma unroll
            for (int j = 0; j < 16; ++j) red[m][q - 1][j][lane] = acc[j];
        }
        __syncthreads();
        if (q == 0 && active) {
#pragma unroll
            for (int j = 0; j < 16; ++j) {
                float v = acc[j] + red[m][0][j][lane] + red[m][1][j][lane]
                                 + red[m][2][j][lane];
                const int row = (j & 3) + 8 * (j >> 2) + 4 * khl;  // C/D layout
                const int sr  = mb + m * 32 + row;
                if (sr < ns) {
                    float o = v + biasv;
                    out[(size_t)list[sr] * OUT_DIM + oc0 + l31] = o > 0.f ? o : 0.f;
                }
            }
        }
        __syncthreads();                  // tiles reused by next chunk
    }
}

extern "C" void kernel_launch(void* const* d_in, const int* in_sizes, int n_in,
                              void* d_out, int out_size, void* d_ws, size_t ws_size,
                              hipStream_t stream) {
    (void)in_sizes; (void)n_in; (void)out_size; (void)d_ws; (void)ws_size;
    const float* x     = (const float*)d_in[0];
    const int*   state = (const int*)  d_in[1];
    const float* masks = (const float*)d_in[2];
    const float* kern  = (const float*)d_in[3];
    const float* b0    = (const float*)d_in[4];
    float* out = (float*)d_out;

    made_fused2<<<dim3(512), dim3(512), 0, stream>>>(x, state, masks, kern, b0, out);
}

// Round 11
// 43.989 us; speedup vs baseline: 4.9715x; 1.0011x over previous
//
#include <hip/hip_runtime.h>
#include <hip/hip_bf16.h>

// MaskedDenseLayer round 11: fused single kernel, counted-vmcnt LDS staging
// (T3/T4), register-budgeted (<128 VGPR) after round 10's spill (WRITE 75MB).
//
// out[b,o] = relu(sum_i x[b,i]*kernel[i,o]*masks[state[b],i,o] + b0[o])
//
// Grid 512 = (s = bid>>5, ot = bid&31); same-ot blocks (bid stride 32) land
// on the same XCD -> kern col-slice stays in that L2.
// Block 512 thr = 8 waves = (q: 16-row k-slice) x (m: 32-sample frag).
// K = 13 stages of 64 rows (stage 12 = rows 768..783 x4 dup; q==0 consumes).
// Per stage per wave: exactly 2 global_load_lds dwordx4 (kern+mask, 1KB
// each, wave-uniform LDS base, 3-buffer ring).
// Schedule/iter t: vmcnt(2) [stage t done, t+1 in flight] -> s_barrier ->
// sched_barrier(0) -> issue stage t+2 -> consume t. Drain (vmcnt 0) only at
// t==12. Ring safety: stage(t+2) overwrites buf of t-1, whose consumers'
// ds_reads completed before the barrier this issue follows.
// vmcnt purity: ALL A-data loads (a1 cvt'd + p2 raw float4) + bias are
// issued BEFORE the prologue stages -> oldest; iter-0's vmcnt(2) drains
// them alongside stage 0's cold miss. p2 -> bf16 cvt at t==6 (frees 48 VGPR).
// Consume: 16 ds_read_b32 (bank==col, 2-way only) + mul + f2bf + 1
// mfma_f32_32x32x16_bf16. K-slices reduced via LDS alias; bias+relu store.

#define IN_DIM 784
#define OUT_DIM 1024
#define BS 512

typedef __attribute__((ext_vector_type(8))) short bf16x8;
typedef __attribute__((ext_vector_type(16))) float f32x16;

static __device__ inline short f2bf(float f) {
    __hip_bfloat16 h = __float2bfloat16(f);   // RNE
    short r; __builtin_memcpy(&r, &h, 2); return r;
}

static __device__ inline void gload_lds16(const float* g, float* lds_base_uniform) {
    __builtin_amdgcn_global_load_lds(
        (const __attribute__((address_space(1))) void*)g,
        (__attribute__((address_space(3))) void*)lds_base_uniform, 16, 0, 0);
}

static __device__ inline bf16x8 pack8(float4 a, float4 b) {
    bf16x8 r;
    r[0]=f2bf(a.x); r[1]=f2bf(a.y); r[2]=f2bf(a.z); r[3]=f2bf(a.w);
    r[4]=f2bf(b.x); r[5]=f2bf(b.y); r[6]=f2bf(b.z); r[7]=f2bf(b.w);
    return r;
}

__global__ __launch_bounds__(512, 4) void made_fused3(
    const float* __restrict__ x,      // [512, 784]
    const int*   __restrict__ state,  // [512]
    const float* __restrict__ masks,  // [16, 784, 1024]
    const float* __restrict__ kern,   // [784, 1024]
    const float* __restrict__ bias,   // [1024]
    float*       __restrict__ out)    // [512, 1024]
{
    __shared__ float tiles[3][2][64][32];   // [buf][kern/mask][row][col] 48 KB
    __shared__ int   list[BS];
    __shared__ int   cnt;

    const int tid  = threadIdx.x;
    const int lane = tid & 63;
    const int w    = tid >> 6;
    const int q    = w & 3;               // 16-row k-slice within a stage
    const int m    = w >> 2;              // sample frag (rows mb+m*32 ..+31)
    const int bid  = blockIdx.x;
    const int s    = bid >> 5;
    const int ot   = bid & 31;
    const int oc0  = ot * 32;
    const int l31  = lane & 31, khl = lane >> 5;

    const float* mS = masks + (size_t)s * IN_DIM * OUT_DIM;

    // ---- build the state's sample list ----
    if (tid == 0) cnt = 0;
    __syncthreads();
    { int st = state[tid]; if (st == s) { int p = atomicAdd(&cnt, 1); list[p] = tid; } }
    __syncthreads();
    const int ns = cnt;

    // stage t into ring buffer b: exactly 2 vm ops per wave, all waves
    auto stage = [&](int t, int b) {
        const int r  = w * 8 + (lane >> 3);           // tile row this lane fills
        const int gr = (t == 12) ? 768 + (r & 15) : t * 64 + r;
        const size_t go = (size_t)gr * OUT_DIM + oc0 + (lane & 7) * 4;
        gload_lds16(kern + go, &tiles[b][0][w * 8][0]);
        gload_lds16(mS   + go, &tiles[b][1][w * 8][0]);
    };

    float (*red)[3][16][64] = (float (*)[3][16][64])tiles;   // 24 KB alias

    for (int mb = 0; mb < ns; mb += 64) {
        const bool active = (mb + m * 32) < ns;

        int r0 = mb + m * 32 + l31; if (r0 >= ns) r0 = ns - 1;
        const float* xr = x + (size_t)list[r0] * IN_DIM;

        // ---- A data, all issued BEFORE staging (vmcnt purity) ----
        bf16x8 a1[7];                     // stages 0..6, converted now (28 VGPR)
#pragma unroll
        for (int t = 0; t < 7; ++t) {
            const int off = t * 64 + q * 16 + khl * 8;
            a1[t] = pack8(*(const float4*)(xr + off), *(const float4*)(xr + off + 4));
        }
        float4 p2[6][2];                  // raw f32 for stages 7..12 (48 VGPR)
#pragma unroll
        for (int u = 0; u < 5; ++u) {
            const int off = (7 + u) * 64 + q * 16 + khl * 8;
            p2[u][0] = *(const float4*)(xr + off);
            p2[u][1] = *(const float4*)(xr + off + 4);
        }
        p2[5][0] = *(const float4*)(xr + 768 + khl * 8);
        p2[5][1] = *(const float4*)(xr + 772 + khl * 8);

        const float biasv = bias[oc0 + l31];

        f32x16 acc;
#pragma unroll
        for (int r = 0; r < 16; ++r) acc[r] = 0.f;

        // ---- prologue: 2 stages in flight ----
        stage(0, 0);
        stage(1, 1);

        bf16x8 a2[6];
#pragma unroll
        for (int t = 0; t < 13; ++t) {
            if (t < 12) asm volatile("s_waitcnt vmcnt(2)" ::: "memory");
            else        asm volatile("s_waitcnt vmcnt(0)" ::: "memory");
            __builtin_amdgcn_s_barrier();
            __builtin_amdgcn_sched_barrier(0);
            if (t + 2 < 13) stage(t + 2, (t + 2) % 3);

            const int buf = t % 3;
            if (active && (t < 12 || q == 0)) {
                bf16x8 bfr;
#pragma unroll
                for (int e = 0; e < 8; ++e) {
                    const int row = ((t < 12) ? q * 16 : 0) + khl * 8 + e;
                    bfr[e] = f2bf(tiles[buf][0][row][l31] * tiles[buf][1][row][l31]);
                }
                bf16x8 av = (t < 7) ? a1[t] : a2[t - 7];
                acc = __builtin_amdgcn_mfma_f32_32x32x16_bf16(av, bfr, acc, 0, 0, 0);
            }
            if (t == 6) {                 // p2 long since drained (iter-0 wait)
#pragma unroll
                for (int u = 0; u < 6; ++u) a2[u] = pack8(p2[u][0], p2[u][1]);
            }
        }

        // ---- reduce 4 k-slices (LDS alias over tiles), bias+relu store ----
        __syncthreads();                  // consume of t=12 done in all waves
        if (q && active) {
#pragma unroll
            for (int j = 0; j < 16; ++j) red[m][q - 1][j][lane] = acc[j];
        }
        __syncthreads();
        if (q == 0 && active) {
#pragma unroll
            for (int j = 0; j < 16; ++j) {
                float v = acc[j] + red[m][0][j][lane] + red[m][1][j][lane]
                                 + red[m][2][j][lane];
                const int row = (j & 3) + 8 * (j >> 2) + 4 * khl;  // C/D layout
                const int sr  = mb + m * 32 + row;
                if (sr < ns) {
                    float o = v + biasv;
                    out[(size_t)list[sr] * OUT_DIM + oc0 + l31] = o > 0.f ? o : 0.f;
                }
            }
        }
        __syncthreads();                  // tiles reused by next chunk
    }
}

extern "C" void kernel_launch(void* const* d_in, const int* in_sizes, int n_in,
                              void* d_out, int out_size, void* d_ws, size_t ws_size,
                              hipStream_t stream) {
    (void)in_sizes; (void)n_in; (void)out_size; (void)d_ws; (void)ws_size;
    const float* x     = (const float*)d_in[0];
    const int*   state = (const int*)  d_in[1];
    const float* masks = (const float*)d_in[2];
    const float* kern  = (const float*)d_in[3];
    const float* b0    = (const float*)d_in[4];
    float* out = (float*)d_out;

    made_fused3<<<dim3(512), dim3(512), 0, stream>>>(x, state, masks, kern, b0, out);
}

// Round 12
// 31.652 us; speedup vs baseline: 6.9092x; 1.3898x over previous
//
#include <hip/hip_runtime.h>
#include <hip/hip_bf16.h>

// MaskedDenseLayer round 12: round-11 counted-vmcnt fused kernel with the
// spill fixed. Rounds 10/11 died to __launch_bounds__(512,4)'s 128-VGPR cap
// (arrays demoted to scratch: WRITE_SIZE 76MB). This is (512,2) = 256 VGPR,
// same occupancy round 8 actually achieved (2 blocks/CU), a[13] converted
// upfront (round-8 style, 92 VGPR there).
//
// Grid 512 = (s = bid>>5, ot = bid&31). Block 512 thr = 8 waves =
// (q: 16-row k-slice) x (m: 32-sample frag). K = 13 stages of 64 rows
// (stage 12 = rows 768..783 x4 dup; only q==0 consumes).
// Per stage per wave: 2 global_load_lds dwordx4 (kern+mask, 1KB, uniform
// LDS base, 3-buffer ring).
// Iter t: vmcnt(2) [stage t landed, t+1 in flight] -> s_barrier ->
// sched_barrier(0) -> issue stage t+2 -> consume t (16 ds_read_b32,
// bank==col 2-way free, mul+f2bf+1 mfma_f32_32x32x16_bf16).
// Drain vmcnt(0) only at t==12. All A/bias loads forced complete before
// the prologue stages -> vmcnt counts stay pure.
// Ring safety: stage(t+2) overwrites buf (t-1)%3, whose consumers' ds_reads
// completed before the barrier this issue follows.

#define IN_DIM 784
#define OUT_DIM 1024
#define BS 512

typedef __attribute__((ext_vector_type(8))) short bf16x8;
typedef __attribute__((ext_vector_type(16))) float f32x16;

static __device__ inline short f2bf(float f) {
    __hip_bfloat16 h = __float2bfloat16(f);   // RNE
    short r; __builtin_memcpy(&r, &h, 2); return r;
}

static __device__ inline void gload_lds16(const float* g, float* lds_base_uniform) {
    __builtin_amdgcn_global_load_lds(
        (const __attribute__((address_space(1))) void*)g,
        (__attribute__((address_space(3))) void*)lds_base_uniform, 16, 0, 0);
}

static __device__ inline bf16x8 pack8(float4 a, float4 b) {
    bf16x8 r;
    r[0]=f2bf(a.x); r[1]=f2bf(a.y); r[2]=f2bf(a.z); r[3]=f2bf(a.w);
    r[4]=f2bf(b.x); r[5]=f2bf(b.y); r[6]=f2bf(b.z); r[7]=f2bf(b.w);
    return r;
}

__global__ __launch_bounds__(512, 2) void made_fused4(
    const float* __restrict__ x,      // [512, 784]
    const int*   __restrict__ state,  // [512]
    const float* __restrict__ masks,  // [16, 784, 1024]
    const float* __restrict__ kern,   // [784, 1024]
    const float* __restrict__ bias,   // [1024]
    float*       __restrict__ out)    // [512, 1024]
{
    __shared__ float tiles[3][2][64][32];   // [buf][kern/mask][row][col] 48 KB
    __shared__ int   list[BS];
    __shared__ int   cnt;

    const int tid  = threadIdx.x;
    const int lane = tid & 63;
    const int w    = tid >> 6;
    const int q    = w & 3;               // 16-row k-slice within a stage
    const int m    = w >> 2;              // sample frag (rows mb+m*32 ..+31)
    const int bid  = blockIdx.x;
    const int s    = bid >> 5;
    const int ot   = bid & 31;
    const int oc0  = ot * 32;
    const int l31  = lane & 31, khl = lane >> 5;

    const float* mS = masks + (size_t)s * IN_DIM * OUT_DIM;

    // ---- build the state's sample list ----
    if (tid == 0) cnt = 0;
    __syncthreads();
    { int st = state[tid]; if (st == s) { int p = atomicAdd(&cnt, 1); list[p] = tid; } }
    __syncthreads();
    const int ns = cnt;

    // stage t into ring buffer b: exactly 2 vm ops per wave, all waves
    auto stage = [&](int t, int b) {
        const int r  = w * 8 + (lane >> 3);           // tile row this lane fills
        const int gr = (t == 12) ? 768 + (r & 15) : t * 64 + r;
        const size_t go = (size_t)gr * OUT_DIM + oc0 + (lane & 7) * 4;
        gload_lds16(kern + go, &tiles[b][0][w * 8][0]);
        gload_lds16(mS   + go, &tiles[b][1][w * 8][0]);
    };

    float (*red)[3][16][64] = (float (*)[3][16][64])tiles;   // 24 KB alias

    for (int mb = 0; mb < ns; mb += 64) {
        const bool active = (mb + m * 32) < ns;

        int r0 = mb + m * 32 + l31; if (r0 >= ns) r0 = ns - 1;
        const float* xr = x + (size_t)list[r0] * IN_DIM;

        // ---- A preload: 13 bf16x8, converted now -> all loads complete
        //      before the prologue stages (vmcnt purity) ----
        bf16x8 a[13];
#pragma unroll
        for (int t = 0; t < 12; ++t) {
            const int off = t * 64 + q * 16 + khl * 8;
            a[t] = pack8(*(const float4*)(xr + off), *(const float4*)(xr + off + 4));
        }
        a[12] = pack8(*(const float4*)(xr + 768 + khl * 8),
                      *(const float4*)(xr + 772 + khl * 8));

        float biasv = bias[oc0 + l31];
        asm volatile("" : "+v"(biasv));   // materialize now (drain its load)

        f32x16 acc;
#pragma unroll
        for (int r = 0; r < 16; ++r) acc[r] = 0.f;

        // ---- prologue: 2 stages in flight ----
        stage(0, 0);
        stage(1, 1);

#pragma unroll
        for (int t = 0; t < 13; ++t) {
            if (t < 12) asm volatile("s_waitcnt vmcnt(2)" ::: "memory");
            else        asm volatile("s_waitcnt vmcnt(0)" ::: "memory");
            __builtin_amdgcn_s_barrier();
            __builtin_amdgcn_sched_barrier(0);
            if (t + 2 < 13) stage(t + 2, (t + 2) % 3);

            const int buf = t % 3;
            if (active && (t < 12 || q == 0)) {
                bf16x8 bfr;
#pragma unroll
                for (int e = 0; e < 8; ++e) {
                    const int row = ((t < 12) ? q * 16 : 0) + khl * 8 + e;
                    bfr[e] = f2bf(tiles[buf][0][row][l31] * tiles[buf][1][row][l31]);
                }
                acc = __builtin_amdgcn_mfma_f32_32x32x16_bf16(a[t], bfr, acc, 0, 0, 0);
            }
        }

        // ---- reduce 4 k-slices (LDS alias over tiles), bias+relu store ----
        __syncthreads();                  // all consumes of t=12 done
        if (q && active) {
#pragma unroll
            for (int j = 0; j < 16; ++j) red[m][q - 1][j][lane] = acc[j];
        }
        __syncthreads();
        if (q == 0 && active) {
#pragma unroll
            for (int j = 0; j < 16; ++j) {
                float v = acc[j] + red[m][0][j][lane] + red[m][1][j][lane]
                                 + red[m][2][j][lane];
                const int row = (j & 3) + 8 * (j >> 2) + 4 * khl;  // C/D layout
                const int sr  = mb + m * 32 + row;
                if (sr < ns) {
                    float o = v + biasv;
                    out[(size_t)list[sr] * OUT_DIM + oc0 + l31] = o > 0.f ? o : 0.f;
                }
            }
        }
        __syncthreads();                  // tiles reused by next chunk
    }
}

extern "C" void kernel_launch(void* const* d_in, const int* in_sizes, int n_in,
                              void* d_out, int out_size, void* d_ws, size_t ws_size,
                              hipStream_t stream) {
    (void)in_sizes; (void)n_in; (void)out_size; (void)d_ws; (void)ws_size;
    const float* x     = (const float*)d_in[0];
    const int*   state = (const int*)  d_in[1];
    const float* masks = (const float*)d_in[2];
    const float* kern  = (const float*)d_in[3];
    const float* b0    = (const float*)d_in[4];
    float* out = (float*)d_out;

    made_fused4<<<dim3(512), dim3(512), 0, stream>>>(x, state, masks, kern, b0, out);
}